// Round 2
// baseline (3145.358 us; speedup 1.0000x reference)
//
#include <hip/hip_runtime.h>

#define NNODES 100000
#define NEDGES 300000
#define KF     1433
#define KP     1536   // 24*64, zero-padded tail
#define HID    16
#define NC     7
#define ROWS   4      // rows per wave

// ---------------------------------------------------------------------------
// Kernel A: y = x @ w1.  1024 threads (16 waves, 4 waves/SIMD), 4 rows/wave,
// depth-2 register prefetch on x, W1^T staged in LDS (96 KB), transpose-
// reduce epilogue (17 shfl/row).
// ---------------------------------------------------------------------------
__global__ __launch_bounds__(1024, 4) void gemm_xw1(const float* __restrict__ x,
                                                    const float* __restrict__ w1,
                                                    float* __restrict__ y) {
    __shared__ float w1t[HID * KP];  // [j][k]

    const int tid = threadIdx.x;

    // Stage w1 transposed + zero-pad k in [KF, KP)
    for (int k0 = tid; k0 < KP; k0 += 1024) {
        if (k0 < KF) {
            const float4* w4 = (const float4*)(w1 + k0 * HID);
            const float4 a = w4[0], b = w4[1], c = w4[2], d = w4[3];
            w1t[ 0*KP+k0]=a.x; w1t[ 1*KP+k0]=a.y; w1t[ 2*KP+k0]=a.z; w1t[ 3*KP+k0]=a.w;
            w1t[ 4*KP+k0]=b.x; w1t[ 5*KP+k0]=b.y; w1t[ 6*KP+k0]=b.z; w1t[ 7*KP+k0]=b.w;
            w1t[ 8*KP+k0]=c.x; w1t[ 9*KP+k0]=c.y; w1t[10*KP+k0]=c.z; w1t[11*KP+k0]=c.w;
            w1t[12*KP+k0]=d.x; w1t[13*KP+k0]=d.y; w1t[14*KP+k0]=d.z; w1t[15*KP+k0]=d.w;
        } else {
            #pragma unroll
            for (int j = 0; j < HID; ++j) w1t[j * KP + k0] = 0.f;
        }
    }
    __syncthreads();

    const int lane = tid & 63;
    const int wid  = blockIdx.x * 16 + (tid >> 6);
    // inverse of the bit-reversed j mapping produced by the halving reduce
    const int jout = ((lane & 1) << 3) | ((lane & 2) << 1) | ((lane & 4) >> 1) | ((lane & 8) >> 3);

    for (int base = wid * ROWS; base < NNODES; base += 4096 * ROWS) {
        const float* px = x + (size_t)base * KF;

        float acc[ROWS][HID];
        #pragma unroll
        for (int r = 0; r < ROWS; ++r)
            #pragma unroll
            for (int j = 0; j < HID; ++j) acc[r][j] = 0.f;

        float xa[ROWS], xb[ROWS];

        auto ld = [&](float* dst, int it) {
            const int k = lane + it * 64;
            #pragma unroll
            for (int r = 0; r < ROWS; ++r)
                dst[r] = (k < KF) ? px[(size_t)r * KF + k] : 0.f;
        };
        auto fmab = [&](const float* xv, int it) {
            const int k = lane + it * 64;
            #pragma unroll
            for (int j = 0; j < HID; ++j) {
                const float wv = w1t[j * KP + k];
                #pragma unroll
                for (int r = 0; r < ROWS; ++r) acc[r][j] += xv[r] * wv;
            }
        };

        ld(xa, 0);
        ld(xb, 1);
        for (int it = 0; it < 22; it += 2) {
            fmab(xa, it);     ld(xa, it + 2);   // loads for it+2 fly during fmab(xb)
            fmab(xb, it + 1); ld(xb, it + 3);
        }
        fmab(xa, 22);   // it=23 is all zeros (k >= 1472 > KF) — skipped

        // Transpose-reduce: 16 values x 64 lanes -> lane (jout) holds column sum
        #pragma unroll
        for (int r = 0; r < ROWS; ++r) {
            float v[HID];
            #pragma unroll
            for (int j = 0; j < HID; ++j) v[j] = acc[r][j];
            #pragma unroll
            for (int s = 0; s < 4; ++s) {
                const int d    = 1 << s;
                const int half = 8 >> s;
                const int sel  = (lane >> s) & 1;
                #pragma unroll
                for (int m = 0; m < half; ++m) {
                    const float send = sel ? v[m] : v[m + half];
                    const float keep = sel ? v[m + half] : v[m];
                    v[m] = keep + __shfl_xor(send, d);
                }
            }
            float t = v[0];
            t += __shfl_xor(t, 16);
            t += __shfl_xor(t, 32);
            if (lane < HID) y[(size_t)(base + r) * HID + jout] = t;
        }
    }
}

// ---------------------------------------------------------------------------
// Kernel B: zero the aggregation buffer
// ---------------------------------------------------------------------------
__global__ __launch_bounds__(256) void zero_agg(float4* __restrict__ agg4) {
    const int i = blockIdx.x * 256 + threadIdx.x;
    if (i < NNODES * HID / 4) agg4[i] = make_float4(0.f, 0.f, 0.f, 0.f);
}

// ---------------------------------------------------------------------------
// Kernel C: agg[dst] += y[src]  (thread per (edge, j))
// ---------------------------------------------------------------------------
__global__ __launch_bounds__(256) void scatter_add(const int* __restrict__ ei,
                                                   const float* __restrict__ y,
                                                   float* __restrict__ agg) {
    const int t = blockIdx.x * 256 + threadIdx.x;
    const int e = t >> 4;
    const int j = t & 15;
    if (e < NEDGES) {
        const int s = ei[e];           // src
        const int d = ei[NEDGES + e];  // dst
        atomicAdd(agg + d * HID + j, y[s * HID + j]);
    }
}

// ---------------------------------------------------------------------------
// Kernel D: out = sigmoid(relu((1+eps)*y + agg + b1) @ w2 + b2)
// ---------------------------------------------------------------------------
__global__ __launch_bounds__(256) void mlp_tail(const float* __restrict__ y,
                                                const float* __restrict__ agg,
                                                const float* __restrict__ b1,
                                                const float* __restrict__ w2,
                                                const float* __restrict__ b2,
                                                const float* __restrict__ epsp,
                                                float* __restrict__ out) {
    __shared__ float sw2[HID * NC];
    __shared__ float sb1[HID];
    __shared__ float sb2[NC];
    __shared__ float seps;

    const int t = threadIdx.x;
    if (t < HID * NC) sw2[t] = w2[t];
    if (t < HID)      sb1[t] = b1[t];
    if (t < NC)       sb2[t] = b2[t];
    if (t == 0)       seps = epsp[0];
    __syncthreads();

    const int i = blockIdx.x * 256 + t;
    if (i >= NNODES) return;

    const float co = 1.f + seps;
    const float4* y4 = (const float4*)(y + i * HID);
    const float4* a4 = (const float4*)(agg + i * HID);

    float h[HID];
    #pragma unroll
    for (int q = 0; q < 4; ++q) {
        const float4 yv = y4[q];
        const float4 av = a4[q];
        h[q * 4 + 0] = fmaxf(co * yv.x + av.x + sb1[q * 4 + 0], 0.f);
        h[q * 4 + 1] = fmaxf(co * yv.y + av.y + sb1[q * 4 + 1], 0.f);
        h[q * 4 + 2] = fmaxf(co * yv.z + av.z + sb1[q * 4 + 2], 0.f);
        h[q * 4 + 3] = fmaxf(co * yv.w + av.w + sb1[q * 4 + 3], 0.f);
    }

    #pragma unroll
    for (int c = 0; c < NC; ++c) {
        float s = sb2[c];
        #pragma unroll
        for (int j = 0; j < HID; ++j) s += h[j] * sw2[j * NC + c];
        out[i * NC + c] = 1.f / (1.f + __expf(-s));
    }
}

// ---------------------------------------------------------------------------
extern "C" void kernel_launch(void* const* d_in, const int* in_sizes, int n_in,
                              void* d_out, int out_size, void* d_ws, size_t ws_size,
                              hipStream_t stream) {
    const float* x   = (const float*)d_in[0];
    const int*   ei  = (const int*)d_in[1];
    const float* w1  = (const float*)d_in[2];
    const float* b1  = (const float*)d_in[3];
    const float* w2  = (const float*)d_in[4];
    const float* b2  = (const float*)d_in[5];
    const float* eps = (const float*)d_in[6];
    float* out = (float*)d_out;

    float* y   = (float*)d_ws;                  // NNODES*HID floats (6.4 MB)
    float* agg = y + (size_t)NNODES * HID;      // NNODES*HID floats (6.4 MB)

    gemm_xw1<<<256, 1024, 0, stream>>>(x, w1, y);
    zero_agg<<<(NNODES * HID / 4 + 255) / 256, 256, 0, stream>>>((float4*)agg);
    scatter_add<<<(NEDGES * 16 + 255) / 256, 256, 0, stream>>>(ei, y, agg);
    mlp_tail<<<(NNODES + 255) / 256, 256, 0, stream>>>(y, agg, b1, w2, b2, eps, out);
}